// Round 8
// baseline (101.035 us; speedup 1.0000x reference)
//
#include <hip/hip_runtime.h>
#include <hip/hip_bf16.h>

#define NB 8
#define NN 512
#define NS 64
#define NH 16
#define ND 256

typedef __attribute__((ext_vector_type(8))) short bf16x8;
typedef __attribute__((ext_vector_type(4))) short bf16x4;
typedef __attribute__((ext_vector_type(4))) float f32x4;

__device__ inline float wred(float v) {
#pragma unroll
  for (int m = 32; m; m >>= 1) v += __shfl_xor(v, m, 64);
  return v;
}
__device__ inline float wred16(float v) {
#pragma unroll
  for (int m = 1; m < 16; m <<= 1) v += __shfl_xor(v, m, 64);
  return v;
}
__device__ inline ushort f2bf(float x) {
  __hip_bfloat16 h = __float2bfloat16(x);
  return *(ushort*)&h;
}

// =====================================================================
// K1: prep — same roles as the 76 µs build, but with XCD-aligned block
// swizzles: every block working on batch b runs with (blk&7)==b, so
// producer and consumer L2 traffic stays on one XCD.
// =====================================================================
__global__ __launch_bounds__(256) void k_prep(const int* __restrict__ pos,
                                              const float* __restrict__ emb,
                                              const float* __restrict__ H,
                                              const float* __restrict__ A,
                                              __hip_bfloat16* __restrict__ spb,
                                              __hip_bfloat16* __restrict__ Ab,
                                              __hip_bfloat16* __restrict__ Hb,
                                              __hip_bfloat16* __restrict__ HT,
                                              float* __restrict__ rdeg,
                                              float* __restrict__ h2) {
  __shared__ ushort T[64][68];
  int blk = blockIdx.x, tid = threadIdx.x;
  int wave = tid >> 6, lane = tid & 63;

  if (blk < 1024) {
    int q = blk;
    int qs = (q & 7) * 128 + (q >> 3);     // b = qs>>7 = q&7
    int t = qs * 256 + tid;                // [0, NB*NN*NS)
    int idx = pos[t];
    __hip_bfloat16* dst = spb + (size_t)t * NH;
    union { bf16x8 v; ushort h[8]; } u0, u1;
    if (idx == 0) {
#pragma unroll
      for (int i = 0; i < 8; ++i) { u0.h[i] = 0; u1.h[i] = 0; }
    } else {
      const float* er = emb + idx * NH;
#pragma unroll
      for (int i = 0; i < 8; ++i) { u0.h[i] = f2bf(er[i]); u1.h[i] = f2bf(er[8 + i]); }
    }
    *(bf16x8*)(void*)dst = u0.v;
    *(bf16x8*)(void*)(dst + 8) = u1.v;
  } else if (blk < 2048) {
    int q = blk - 1024;
    int qs = (q & 7) * 128 + (q >> 3);     // row = qs*4+wave -> b = q&7
    int row = qs * 4 + wave;               // [0, NB*NN)
    const float* ar = A + (size_t)row * NN;
    float4 v0 = *(const float4*)(ar + lane * 8);
    float4 v1 = *(const float4*)(ar + lane * 8 + 4);
    float s = v0.x + v0.y + v0.z + v0.w + v1.x + v1.y + v1.z + v1.w;
    union { bf16x8 v; ushort h[8]; } u;
    u.h[0] = f2bf(v0.x); u.h[1] = f2bf(v0.y); u.h[2] = f2bf(v0.z); u.h[3] = f2bf(v0.w);
    u.h[4] = f2bf(v1.x); u.h[5] = f2bf(v1.y); u.h[6] = f2bf(v1.z); u.h[7] = f2bf(v1.w);
    *(bf16x8*)(void*)(Ab + (size_t)row * NN + lane * 8) = u.v;
    s = wred(s);
    if (lane == 0) rdeg[row] = rsqrtf(s);
  } else if (blk < 3072) {
    int q = blk - 2048;
    int qs = (q & 7) * 128 + (q >> 3);
    int row = qs * 4 + wave;               // [0, NB*NN)
    const float* hr = H + (size_t)row * ND;
    float4 v = *(const float4*)(hr + lane * 4);
    float ss = v.x * v.x + v.y * v.y + v.z * v.z + v.w * v.w;
    union { bf16x4 v4; ushort h[4]; } u;
    u.h[0] = f2bf(v.x); u.h[1] = f2bf(v.y); u.h[2] = f2bf(v.z); u.h[3] = f2bf(v.w);
    *(bf16x4*)(void*)(Hb + (size_t)row * ND + lane * 4) = u.v4;
    ss = wred(ss);
    if (lane == 0) h2[row] = ss;
  } else {
    int bi = blk - 3072;                   // [0, 256)
    int bis = (bi & 7) * 32 + (bi >> 3);   // b = bis>>5 = bi&7
    int b = bis >> 5, r = bis & 31;
    int d0 = (r >> 3) * 64, n0 = (r & 7) * 64;
    int n = tid >> 2, c = (tid & 3) * 16;
    const float* src = H + ((size_t)b * NN + n0 + n) * ND + d0 + c;
#pragma unroll
    for (int q = 0; q < 4; ++q) {
      float4 f = *(const float4*)(src + q * 4);
      T[n][c + q * 4 + 0] = f2bf(f.x);
      T[n][c + q * 4 + 1] = f2bf(f.y);
      T[n][c + q * 4 + 2] = f2bf(f.z);
      T[n][c + q * 4 + 3] = f2bf(f.w);
    }
    __syncthreads();
    int d = tid >> 2, nc = (tid & 3) * 16;
    union { bf16x8 v; ushort h[8]; } o0, o1;
#pragma unroll
    for (int i = 0; i < 8; ++i) { o0.h[i] = T[nc + i][d]; o1.h[i] = T[nc + 8 + i][d]; }
    __hip_bfloat16* dst = HT + ((size_t)b * ND + d0 + d) * NN + n0 + nc;
    *(bf16x8*)(void*)dst = o0.v;
    *(bf16x8*)(void*)(dst + 8) = o1.v;
  }
}

// =====================================================================
// K2: M = rdeg ⊙ (A·H) — identical to the 76 µs build.
// =====================================================================
__global__ __launch_bounds__(256) void k_gemmM(const __hip_bfloat16* __restrict__ Ab,
                                               const __hip_bfloat16* __restrict__ HT,
                                               const float* __restrict__ rdeg,
                                               __hip_bfloat16* __restrict__ Mb,
                                               float* __restrict__ m2p) {
  int wave = threadIdx.x >> 6, lane = threadIdx.x & 63;
  int b = blockIdx.x & 7, t = blockIdx.x >> 3;   // t in [0,32)
  int tile = t * 4 + wave;                       // [0,128)
  int rt = tile >> 3, ct = tile & 7;
  int r0 = rt * 32, c0 = ct * 32;
  int rl = lane & 15, g4 = lane >> 4;
  const __hip_bfloat16* X = Ab + (size_t)b * NN * NN;
  const __hip_bfloat16* Y = HT + (size_t)b * ND * NN;
  f32x4 acc[2][2];
#pragma unroll
  for (int i = 0; i < 2; ++i)
#pragma unroll
    for (int j = 0; j < 2; ++j) { acc[i][j][0] = 0.f; acc[i][j][1] = 0.f; acc[i][j][2] = 0.f; acc[i][j][3] = 0.f; }
#pragma unroll
  for (int kk = 0; kk < NN / 32; ++kk) {
    int kb = kk * 32 + g4 * 8;
    bf16x8 a[2], bv[2];
#pragma unroll
    for (int i = 0; i < 2; ++i)
      a[i] = *(const bf16x8*)(const void*)(X + (size_t)(r0 + i * 16 + rl) * NN + kb);
#pragma unroll
    for (int j = 0; j < 2; ++j)
      bv[j] = *(const bf16x8*)(const void*)(Y + (size_t)(c0 + j * 16 + rl) * NN + kb);
#pragma unroll
    for (int i = 0; i < 2; ++i)
#pragma unroll
      for (int j = 0; j < 2; ++j)
        acc[i][j] = __builtin_amdgcn_mfma_f32_16x16x32_bf16(a[i], bv[j], acc[i][j], 0, 0, 0);
  }
#pragma unroll
  for (int i = 0; i < 2; ++i)
#pragma unroll
    for (int r = 0; r < 4; ++r) {
      int row = r0 + i * 16 + g4 * 4 + r;
      float rd = rdeg[b * NN + row];
      float ss = 0.f;
#pragma unroll
      for (int j = 0; j < 2; ++j) {
        float m = rd * acc[i][j][r];
        int col = c0 + j * 16 + rl;
        Mb[((size_t)b * NN + row) * ND + col] = __float2bfloat16(m);
        ss += m * m;
      }
      ss = wred16(ss);
      if (rl == 0) m2p[(size_t)ct * (NB * NN) + b * NN + row] = ss;
    }
}

// =====================================================================
// K3a: G ONCE to global ws. 512 blocks x 256 thr = (b, rt, ct).
// Wave w: rows w*16..+15 of the 64x64 tile. Tiny LDS (h2s/m2s), 1 barrier.
// =====================================================================
__global__ __launch_bounds__(256) void k_gauss(const __hip_bfloat16* __restrict__ Hb,
                                               const __hip_bfloat16* __restrict__ Mb,
                                               const float* __restrict__ h2,
                                               const float* __restrict__ m2p,
                                               const float* __restrict__ sigma,
                                               float* __restrict__ G) {
  __shared__ float h2s[64], m2s[64];
  int b = blockIdx.x & 7;
  int t2 = blockIdx.x >> 3;                 // [0,64)
  int ct = t2 & 7, rt = t2 >> 3;
  int r0 = rt * 64, c0 = ct * 64;
  int tid = threadIdx.x;
  int wave = tid >> 6, lane = tid & 63;
  int rl = lane & 15, g4 = lane >> 4;

  if (tid < 64) {
    h2s[tid] = h2[b * NN + r0 + tid];
  } else if (tid < 128) {
    int c = tid - 64;
    float s = 0.f;
#pragma unroll
    for (int p = 0; p < 8; ++p) s += m2p[(size_t)p * (NB * NN) + b * NN + c0 + c];
    m2s[c] = s;
  }
  __syncthreads();

  const __hip_bfloat16* X = Hb + (size_t)b * NN * ND;
  const __hip_bfloat16* Y = Mb + (size_t)b * NN * ND;
  int rw = wave * 16;
  f32x4 acc[4];
#pragma unroll
  for (int j = 0; j < 4; ++j) { acc[j][0] = 0.f; acc[j][1] = 0.f; acc[j][2] = 0.f; acc[j][3] = 0.f; }
#pragma unroll
  for (int kk = 0; kk < ND / 32; ++kk) {
    int kb = kk * 32 + g4 * 8;
    bf16x8 a = *(const bf16x8*)(const void*)(X + (size_t)(r0 + rw + rl) * ND + kb);
#pragma unroll
    for (int j = 0; j < 4; ++j) {
      bf16x8 bv = *(const bf16x8*)(const void*)(Y + (size_t)(c0 + j * 16 + rl) * ND + kb);
      acc[j] = __builtin_amdgcn_mfma_f32_16x16x32_bf16(a, bv, acc[j], 0, 0, 0);
    }
  }
  float sg = sigma[0];
  float inv = 0.5f / (sg * sg);
  float* Gb = G + (size_t)b * NN * NN;
#pragma unroll
  for (int j = 0; j < 4; ++j)
#pragma unroll
    for (int r = 0; r < 4; ++r) {
      int row = r0 + rw + g4 * 4 + r;
      int col = c0 + j * 16 + rl;
      float d2 = h2s[rw + g4 * 4 + r] + m2s[j * 16 + rl] - 2.0f * acc[j][r];
      Gb[(size_t)row * NN + col] = __expf(-d2 * inv);
    }
}

// =====================================================================
// K3b: gram + G + output. 2048 blocks x 256 thr. NO LDS, NO barriers.
// Block = (b, rt, ct, hg); wave w owns head hg*4+w's 64x64 tile:
// 4x4 acc gram (verified layout), add G (scalar L2-resident reads),
// scalar stores (R3's known-best pattern).
// =====================================================================
__global__ __launch_bounds__(256) void k_out(const __hip_bfloat16* __restrict__ spb,
                                             const float* __restrict__ G,
                                             float* __restrict__ out) {
  int b = blockIdx.x & 7;
  int t2 = blockIdx.x >> 3;                 // [0,256)
  int ct = t2 & 7, rt = (t2 >> 3) & 7, hg = t2 >> 6;
  int r0 = rt * 64, c0 = ct * 64;
  int wave = threadIdx.x >> 6, lane = threadIdx.x & 63;
  int rl = lane & 15, g4 = lane >> 4;
  int h = hg * 4 + wave;

  const __hip_bfloat16* Xs = spb + ((size_t)b * NH + h) * NN * NS;
  f32x4 acc[4][4];
#pragma unroll
  for (int i = 0; i < 4; ++i)
#pragma unroll
    for (int j = 0; j < 4; ++j) { acc[i][j][0] = 0.f; acc[i][j][1] = 0.f; acc[i][j][2] = 0.f; acc[i][j][3] = 0.f; }
#pragma unroll
  for (int kk = 0; kk < NS / 32; ++kk) {
    int kb = kk * 32 + g4 * 8;
    bf16x8 a[4], bv[4];
#pragma unroll
    for (int i = 0; i < 4; ++i)
      a[i] = *(const bf16x8*)(const void*)(Xs + (size_t)(r0 + i * 16 + rl) * NS + kb);
#pragma unroll
    for (int j = 0; j < 4; ++j)
      bv[j] = *(const bf16x8*)(const void*)(Xs + (size_t)(c0 + j * 16 + rl) * NS + kb);
#pragma unroll
    for (int i = 0; i < 4; ++i)
#pragma unroll
      for (int j = 0; j < 4; ++j)
        acc[i][j] = __builtin_amdgcn_mfma_f32_16x16x32_bf16(a[i], bv[j], acc[i][j], 0, 0, 0);
  }
  const float* Gb = G + (size_t)b * NN * NN;
  float* ob = out + ((size_t)b * NH + h) * NN * NN;
#pragma unroll
  for (int i = 0; i < 4; ++i)
#pragma unroll
    for (int j = 0; j < 4; ++j)
#pragma unroll
      for (int r = 0; r < 4; ++r) {
        int row = r0 + i * 16 + g4 * 4 + r;
        int col = c0 + j * 16 + rl;
        ob[(size_t)row * NN + col] = acc[i][j][r] + Gb[(size_t)row * NN + col];
      }
}

extern "C" void kernel_launch(void* const* d_in, const int* in_sizes, int n_in,
                              void* d_out, int out_size, void* d_ws, size_t ws_size,
                              hipStream_t stream) {
  const int* pos = (const int*)d_in[0];
  const float* H = (const float*)d_in[1];
  const float* A = (const float*)d_in[2];
  const float* sigma = (const float*)d_in[3];
  const float* emb = (const float*)d_in[4];
  // d_in[5] (vt_weight) only affects the sliced-off padded row/col -> unused.
  float* out = (float*)d_out;

  char* ws = (char*)d_ws;
  size_t off = 0;
  auto alloc = [&](size_t bytes) -> void* {
    void* p = ws + off;
    off = (off + bytes + 255) & ~(size_t)255;
    return p;
  };
  __hip_bfloat16* spb = (__hip_bfloat16*)alloc((size_t)NB * NH * NN * NS * 2);
  __hip_bfloat16* Ab  = (__hip_bfloat16*)alloc((size_t)NB * NN * NN * 2);
  __hip_bfloat16* Hb  = (__hip_bfloat16*)alloc((size_t)NB * NN * ND * 2);
  __hip_bfloat16* HT  = (__hip_bfloat16*)alloc((size_t)NB * ND * NN * 2);
  __hip_bfloat16* Mb  = (__hip_bfloat16*)alloc((size_t)NB * NN * ND * 2);
  float* Gws  = (float*)alloc((size_t)NB * NN * NN * 4);
  float* m2p  = (float*)alloc((size_t)8 * NB * NN * 4);
  float* rdeg = (float*)alloc((size_t)NB * NN * 4);
  float* h2   = (float*)alloc((size_t)NB * NN * 4);

  k_prep<<<3328, 256, 0, stream>>>(pos, emb, H, A, spb, Ab, Hb, HT, rdeg, h2);
  k_gemmM<<<256, 256, 0, stream>>>(Ab, HT, rdeg, Mb, m2p);
  k_gauss<<<512, 256, 0, stream>>>(Hb, Mb, h2, m2p, sigma, Gws);
  k_out<<<2048, 256, 0, stream>>>(spb, Gws, out);
}

// Round 9
// 98.103 us; speedup vs baseline: 1.0299x; 1.0299x over previous
//
#include <hip/hip_runtime.h>
#include <hip/hip_bf16.h>

#define NB 8
#define NN 512
#define NS 64
#define NH 16
#define ND 256

typedef __attribute__((ext_vector_type(8))) short bf16x8;
typedef __attribute__((ext_vector_type(4))) short bf16x4;
typedef __attribute__((ext_vector_type(4))) float f32x4;

__device__ inline float wred(float v) {
#pragma unroll
  for (int m = 32; m; m >>= 1) v += __shfl_xor(v, m, 64);
  return v;
}
__device__ inline float wred16(float v) {
#pragma unroll
  for (int m = 1; m < 16; m <<= 1) v += __shfl_xor(v, m, 64);
  return v;
}
__device__ inline ushort f2bf(float x) {
  __hip_bfloat16 h = __float2bfloat16(x);
  return *(ushort*)&h;
}

// =====================================================================
// K1: prep — identical to the 76 µs round-3 build (swizzle reverted).
// =====================================================================
__global__ __launch_bounds__(256) void k_prep(const int* __restrict__ pos,
                                              const float* __restrict__ emb,
                                              const float* __restrict__ H,
                                              const float* __restrict__ A,
                                              __hip_bfloat16* __restrict__ spb,
                                              __hip_bfloat16* __restrict__ Ab,
                                              __hip_bfloat16* __restrict__ Hb,
                                              __hip_bfloat16* __restrict__ HT,
                                              float* __restrict__ rdeg,
                                              float* __restrict__ h2) {
  __shared__ ushort T[64][68];
  int blk = blockIdx.x, tid = threadIdx.x;
  int wave = tid >> 6, lane = tid & 63;

  if (blk < 1024) {
    int t = blk * 256 + tid;               // [0, NB*NN*NS)
    int idx = pos[t];
    __hip_bfloat16* dst = spb + (size_t)t * NH;
    union { bf16x8 v; ushort h[8]; } u0, u1;
    if (idx == 0) {
#pragma unroll
      for (int i = 0; i < 8; ++i) { u0.h[i] = 0; u1.h[i] = 0; }
    } else {
      const float* er = emb + idx * NH;
#pragma unroll
      for (int i = 0; i < 8; ++i) { u0.h[i] = f2bf(er[i]); u1.h[i] = f2bf(er[8 + i]); }
    }
    *(bf16x8*)(void*)dst = u0.v;
    *(bf16x8*)(void*)(dst + 8) = u1.v;
  } else if (blk < 2048) {
    int row = (blk - 1024) * 4 + wave;     // [0, NB*NN)
    const float* ar = A + (size_t)row * NN;
    float4 v0 = *(const float4*)(ar + lane * 8);
    float4 v1 = *(const float4*)(ar + lane * 8 + 4);
    float s = v0.x + v0.y + v0.z + v0.w + v1.x + v1.y + v1.z + v1.w;
    union { bf16x8 v; ushort h[8]; } u;
    u.h[0] = f2bf(v0.x); u.h[1] = f2bf(v0.y); u.h[2] = f2bf(v0.z); u.h[3] = f2bf(v0.w);
    u.h[4] = f2bf(v1.x); u.h[5] = f2bf(v1.y); u.h[6] = f2bf(v1.z); u.h[7] = f2bf(v1.w);
    *(bf16x8*)(void*)(Ab + (size_t)row * NN + lane * 8) = u.v;
    s = wred(s);
    if (lane == 0) rdeg[row] = rsqrtf(s);
  } else if (blk < 3072) {
    int row = (blk - 2048) * 4 + wave;     // [0, NB*NN)
    const float* hr = H + (size_t)row * ND;
    float4 v = *(const float4*)(hr + lane * 4);
    float ss = v.x * v.x + v.y * v.y + v.z * v.z + v.w * v.w;
    union { bf16x4 v4; ushort h[4]; } u;
    u.h[0] = f2bf(v.x); u.h[1] = f2bf(v.y); u.h[2] = f2bf(v.z); u.h[3] = f2bf(v.w);
    *(bf16x4*)(void*)(Hb + (size_t)row * ND + lane * 4) = u.v4;
    ss = wred(ss);
    if (lane == 0) h2[row] = ss;
  } else {
    int bi = blk - 3072;                   // [0, 256)
    int b = bi >> 5, r = bi & 31;
    int d0 = (r >> 3) * 64, n0 = (r & 7) * 64;
    int n = tid >> 2, c = (tid & 3) * 16;
    const float* src = H + ((size_t)b * NN + n0 + n) * ND + d0 + c;
#pragma unroll
    for (int q = 0; q < 4; ++q) {
      float4 f = *(const float4*)(src + q * 4);
      T[n][c + q * 4 + 0] = f2bf(f.x);
      T[n][c + q * 4 + 1] = f2bf(f.y);
      T[n][c + q * 4 + 2] = f2bf(f.z);
      T[n][c + q * 4 + 3] = f2bf(f.w);
    }
    __syncthreads();
    int d = tid >> 2, nc = (tid & 3) * 16;
    union { bf16x8 v; ushort h[8]; } o0, o1;
#pragma unroll
    for (int i = 0; i < 8; ++i) { o0.h[i] = T[nc + i][d]; o1.h[i] = T[nc + 8 + i][d]; }
    __hip_bfloat16* dst = HT + ((size_t)b * ND + d0 + d) * NN + n0 + nc;
    *(bf16x8*)(void*)dst = o0.v;
    *(bf16x8*)(void*)(dst + 8) = o1.v;
  }
}

// =====================================================================
// K2: M = rdeg ⊙ (A·H) — identical to the 76 µs round-3 build.
// =====================================================================
__global__ __launch_bounds__(256) void k_gemmM(const __hip_bfloat16* __restrict__ Ab,
                                               const __hip_bfloat16* __restrict__ HT,
                                               const float* __restrict__ rdeg,
                                               __hip_bfloat16* __restrict__ Mb,
                                               float* __restrict__ m2p) {
  int wave = threadIdx.x >> 6, lane = threadIdx.x & 63;
  int b = blockIdx.x & 7, t = blockIdx.x >> 3;   // t in [0,32)
  int tile = t * 4 + wave;                       // [0,128)
  int rt = tile >> 3, ct = tile & 7;
  int r0 = rt * 32, c0 = ct * 32;
  int rl = lane & 15, g4 = lane >> 4;
  const __hip_bfloat16* X = Ab + (size_t)b * NN * NN;
  const __hip_bfloat16* Y = HT + (size_t)b * ND * NN;
  f32x4 acc[2][2];
#pragma unroll
  for (int i = 0; i < 2; ++i)
#pragma unroll
    for (int j = 0; j < 2; ++j) { acc[i][j][0] = 0.f; acc[i][j][1] = 0.f; acc[i][j][2] = 0.f; acc[i][j][3] = 0.f; }
#pragma unroll
  for (int kk = 0; kk < NN / 32; ++kk) {
    int kb = kk * 32 + g4 * 8;
    bf16x8 a[2], bv[2];
#pragma unroll
    for (int i = 0; i < 2; ++i)
      a[i] = *(const bf16x8*)(const void*)(X + (size_t)(r0 + i * 16 + rl) * NN + kb);
#pragma unroll
    for (int j = 0; j < 2; ++j)
      bv[j] = *(const bf16x8*)(const void*)(Y + (size_t)(c0 + j * 16 + rl) * NN + kb);
#pragma unroll
    for (int i = 0; i < 2; ++i)
#pragma unroll
      for (int j = 0; j < 2; ++j)
        acc[i][j] = __builtin_amdgcn_mfma_f32_16x16x32_bf16(a[i], bv[j], acc[i][j], 0, 0, 0);
  }
#pragma unroll
  for (int i = 0; i < 2; ++i)
#pragma unroll
    for (int r = 0; r < 4; ++r) {
      int row = r0 + i * 16 + g4 * 4 + r;
      float rd = rdeg[b * NN + row];
      float ss = 0.f;
#pragma unroll
      for (int j = 0; j < 2; ++j) {
        float m = rd * acc[i][j][r];
        int col = c0 + j * 16 + rl;
        Mb[((size_t)b * NN + row) * ND + col] = __float2bfloat16(m);
        ss += m * m;
      }
      ss = wred16(ss);
      if (rl == 0) m2p[(size_t)ct * (NB * NN) + b * NN + row] = ss;
    }
}

// =====================================================================
// K3 v6: 2048 blocks x 256 thr. Block = (b, rt, ct, hg in [0,4)).
// Phase 1: R3-identical — 4 waves compute G -> Gt (17 KB), ONE barrier.
// Phase 2: wave w does head hg*4+w in FOUR 32x32 quarter-passes with
// acc[2][2] (16 AGPR). Peak live regs ~70-80 (vs 128 in R3-R8) ->
// VGPR-allowed occupancy ~25 waves/CU instead of 16; LDS allows
// 8 blocks/CU. Single change vs R3: register-thin phase 2 for TLP.
// =====================================================================
__global__ __launch_bounds__(256, 4) void k_out(const __hip_bfloat16* __restrict__ Hb,
                                                const __hip_bfloat16* __restrict__ Mb,
                                                const __hip_bfloat16* __restrict__ spb,
                                                const float* __restrict__ h2,
                                                const float* __restrict__ m2p,
                                                const float* __restrict__ sigma,
                                                float* __restrict__ out) {
  __shared__ __align__(16) float Gt[64][68];
  __shared__ float h2s[64], m2s[64];
  int b = blockIdx.x & 7;
  int t2 = blockIdx.x >> 3;                 // [0,256)
  int ct = t2 & 7, rt = (t2 >> 3) & 7, hg = t2 >> 6;  // hg in [0,4)
  int r0 = rt * 64, c0 = ct * 64;
  int tid = threadIdx.x;
  int wave = tid >> 6, lane = tid & 63;
  int rl = lane & 15, g4 = lane >> 4;

  if (tid < 64) {
    h2s[tid] = h2[b * NN + r0 + tid];
  } else if (tid < 128) {
    int c = tid - 64;
    float s = 0.f;
#pragma unroll
    for (int p = 0; p < 8; ++p) s += m2p[(size_t)p * (NB * NN) + b * NN + c0 + c];
    m2s[c] = s;
  }
  __syncthreads();

  // ---- phase 1: G once per block. wave w: rows w*16..+15, all 64 cols.
  {
    const __hip_bfloat16* X = Hb + (size_t)b * NN * ND;
    const __hip_bfloat16* Y = Mb + (size_t)b * NN * ND;
    int rw = wave * 16;
    f32x4 acc[4];
#pragma unroll
    for (int j = 0; j < 4; ++j) { acc[j][0] = 0.f; acc[j][1] = 0.f; acc[j][2] = 0.f; acc[j][3] = 0.f; }
#pragma unroll
    for (int kk = 0; kk < ND / 32; ++kk) {
      int kb = kk * 32 + g4 * 8;
      bf16x8 a = *(const bf16x8*)(const void*)(X + (size_t)(r0 + rw + rl) * ND + kb);
#pragma unroll
      for (int j = 0; j < 4; ++j) {
        bf16x8 bv = *(const bf16x8*)(const void*)(Y + (size_t)(c0 + j * 16 + rl) * ND + kb);
        acc[j] = __builtin_amdgcn_mfma_f32_16x16x32_bf16(a, bv, acc[j], 0, 0, 0);
      }
    }
    float sg = sigma[0];
    float inv = 0.5f / (sg * sg);
#pragma unroll
    for (int j = 0; j < 4; ++j)
#pragma unroll
      for (int r = 0; r < 4; ++r) {
        int rowl = rw + g4 * 4 + r;
        int col = j * 16 + rl;
        float d2 = h2s[rowl] + m2s[col] - 2.0f * acc[j][r];
        Gt[rowl][col] = __expf(-d2 * inv);
      }
  }
  __syncthreads();

  // ---- phase 2: wave w -> head hg*4+w, four 32x32 quarter-passes.
  {
    int h = hg * 4 + wave;
    const __hip_bfloat16* Xs = spb + ((size_t)b * NH + h) * NN * NS;
    float* ob = out + ((size_t)b * NH + h) * NN * NN;
#pragma unroll 1
    for (int qt = 0; qt < 4; ++qt) {
      int qr = (qt >> 1) * 32, qc = (qt & 1) * 32;
      f32x4 acc[2][2];
#pragma unroll
      for (int i = 0; i < 2; ++i)
#pragma unroll
        for (int j = 0; j < 2; ++j) { acc[i][j][0] = 0.f; acc[i][j][1] = 0.f; acc[i][j][2] = 0.f; acc[i][j][3] = 0.f; }
#pragma unroll
      for (int kk = 0; kk < NS / 32; ++kk) {
        int kb = kk * 32 + g4 * 8;
        bf16x8 a[2], bv[2];
#pragma unroll
        for (int i = 0; i < 2; ++i)
          a[i] = *(const bf16x8*)(const void*)(Xs + (size_t)(r0 + qr + i * 16 + rl) * NS + kb);
#pragma unroll
        for (int j = 0; j < 2; ++j)
          bv[j] = *(const bf16x8*)(const void*)(Xs + (size_t)(c0 + qc + j * 16 + rl) * NS + kb);
#pragma unroll
        for (int i = 0; i < 2; ++i)
#pragma unroll
          for (int j = 0; j < 2; ++j)
            acc[i][j] = __builtin_amdgcn_mfma_f32_16x16x32_bf16(a[i], bv[j], acc[i][j], 0, 0, 0);
      }
#pragma unroll
      for (int i = 0; i < 2; ++i)
#pragma unroll
        for (int j = 0; j < 2; ++j)
#pragma unroll
          for (int r = 0; r < 4; ++r) {
            int rowl = qr + i * 16 + g4 * 4 + r;
            int col = qc + j * 16 + rl;
            ob[(size_t)(r0 + rowl) * NN + c0 + col] = acc[i][j][r] + Gt[rowl][col];
          }
    }
  }
}

extern "C" void kernel_launch(void* const* d_in, const int* in_sizes, int n_in,
                              void* d_out, int out_size, void* d_ws, size_t ws_size,
                              hipStream_t stream) {
  const int* pos = (const int*)d_in[0];
  const float* H = (const float*)d_in[1];
  const float* A = (const float*)d_in[2];
  const float* sigma = (const float*)d_in[3];
  const float* emb = (const float*)d_in[4];
  // d_in[5] (vt_weight) only affects the sliced-off padded row/col -> unused.
  float* out = (float*)d_out;

  char* ws = (char*)d_ws;
  size_t off = 0;
  auto alloc = [&](size_t bytes) -> void* {
    void* p = ws + off;
    off = (off + bytes + 255) & ~(size_t)255;
    return p;
  };
  __hip_bfloat16* spb = (__hip_bfloat16*)alloc((size_t)NB * NH * NN * NS * 2);
  __hip_bfloat16* Ab  = (__hip_bfloat16*)alloc((size_t)NB * NN * NN * 2);
  __hip_bfloat16* Hb  = (__hip_bfloat16*)alloc((size_t)NB * NN * ND * 2);
  __hip_bfloat16* HT  = (__hip_bfloat16*)alloc((size_t)NB * ND * NN * 2);
  __hip_bfloat16* Mb  = (__hip_bfloat16*)alloc((size_t)NB * NN * ND * 2);
  float* m2p  = (float*)alloc((size_t)8 * NB * NN * 4);
  float* rdeg = (float*)alloc((size_t)NB * NN * 4);
  float* h2   = (float*)alloc((size_t)NB * NN * 4);

  k_prep<<<3328, 256, 0, stream>>>(pos, emb, H, A, spb, Ab, Hb, HT, rdeg, h2);
  k_gemmM<<<256, 256, 0, stream>>>(Ab, HT, rdeg, Mb, m2p);
  k_out<<<2048, 256, 0, stream>>>(Hb, Mb, spb, h2, m2p, sigma, out);
}

// Round 10
// 70.381 us; speedup vs baseline: 1.4355x; 1.3939x over previous
//
#include <hip/hip_runtime.h>
#include <hip/hip_bf16.h>

#define NB 8
#define NN 512
#define NS 64
#define NH 16
#define ND 256

typedef __attribute__((ext_vector_type(8))) short bf16x8;
typedef __attribute__((ext_vector_type(4))) short bf16x4;
typedef __attribute__((ext_vector_type(4))) float f32x4;

__device__ inline float wred(float v) {
#pragma unroll
  for (int m = 32; m; m >>= 1) v += __shfl_xor(v, m, 64);
  return v;
}
__device__ inline float wred16(float v) {
#pragma unroll
  for (int m = 1; m < 16; m <<= 1) v += __shfl_xor(v, m, 64);
  return v;
}
__device__ inline ushort f2bf(float x) {
  __hip_bfloat16 h = __float2bfloat16(x);
  return *(ushort*)&h;
}

// =====================================================================
// K1: prep — identical to the 76 µs round-3 build.
// =====================================================================
__global__ __launch_bounds__(256) void k_prep(const int* __restrict__ pos,
                                              const float* __restrict__ emb,
                                              const float* __restrict__ H,
                                              const float* __restrict__ A,
                                              __hip_bfloat16* __restrict__ spb,
                                              __hip_bfloat16* __restrict__ Ab,
                                              __hip_bfloat16* __restrict__ Hb,
                                              __hip_bfloat16* __restrict__ HT,
                                              float* __restrict__ rdeg,
                                              float* __restrict__ h2) {
  __shared__ ushort T[64][68];
  int blk = blockIdx.x, tid = threadIdx.x;
  int wave = tid >> 6, lane = tid & 63;

  if (blk < 1024) {
    int t = blk * 256 + tid;               // [0, NB*NN*NS)
    int idx = pos[t];
    __hip_bfloat16* dst = spb + (size_t)t * NH;
    union { bf16x8 v; ushort h[8]; } u0, u1;
    if (idx == 0) {
#pragma unroll
      for (int i = 0; i < 8; ++i) { u0.h[i] = 0; u1.h[i] = 0; }
    } else {
      const float* er = emb + idx * NH;
#pragma unroll
      for (int i = 0; i < 8; ++i) { u0.h[i] = f2bf(er[i]); u1.h[i] = f2bf(er[8 + i]); }
    }
    *(bf16x8*)(void*)dst = u0.v;
    *(bf16x8*)(void*)(dst + 8) = u1.v;
  } else if (blk < 2048) {
    int row = (blk - 1024) * 4 + wave;     // [0, NB*NN)
    const float* ar = A + (size_t)row * NN;
    float4 v0 = *(const float4*)(ar + lane * 8);
    float4 v1 = *(const float4*)(ar + lane * 8 + 4);
    float s = v0.x + v0.y + v0.z + v0.w + v1.x + v1.y + v1.z + v1.w;
    union { bf16x8 v; ushort h[8]; } u;
    u.h[0] = f2bf(v0.x); u.h[1] = f2bf(v0.y); u.h[2] = f2bf(v0.z); u.h[3] = f2bf(v0.w);
    u.h[4] = f2bf(v1.x); u.h[5] = f2bf(v1.y); u.h[6] = f2bf(v1.z); u.h[7] = f2bf(v1.w);
    *(bf16x8*)(void*)(Ab + (size_t)row * NN + lane * 8) = u.v;
    s = wred(s);
    if (lane == 0) rdeg[row] = rsqrtf(s);
  } else if (blk < 3072) {
    int row = (blk - 2048) * 4 + wave;     // [0, NB*NN)
    const float* hr = H + (size_t)row * ND;
    float4 v = *(const float4*)(hr + lane * 4);
    float ss = v.x * v.x + v.y * v.y + v.z * v.z + v.w * v.w;
    union { bf16x4 v4; ushort h[4]; } u;
    u.h[0] = f2bf(v.x); u.h[1] = f2bf(v.y); u.h[2] = f2bf(v.z); u.h[3] = f2bf(v.w);
    *(bf16x4*)(void*)(Hb + (size_t)row * ND + lane * 4) = u.v4;
    ss = wred(ss);
    if (lane == 0) h2[row] = ss;
  } else {
    int bi = blk - 3072;                   // [0, 256)
    int b = bi >> 5, r = bi & 31;
    int d0 = (r >> 3) * 64, n0 = (r & 7) * 64;
    int n = tid >> 2, c = (tid & 3) * 16;
    const float* src = H + ((size_t)b * NN + n0 + n) * ND + d0 + c;
#pragma unroll
    for (int q = 0; q < 4; ++q) {
      float4 f = *(const float4*)(src + q * 4);
      T[n][c + q * 4 + 0] = f2bf(f.x);
      T[n][c + q * 4 + 1] = f2bf(f.y);
      T[n][c + q * 4 + 2] = f2bf(f.z);
      T[n][c + q * 4 + 3] = f2bf(f.w);
    }
    __syncthreads();
    int d = tid >> 2, nc = (tid & 3) * 16;
    union { bf16x8 v; ushort h[8]; } o0, o1;
#pragma unroll
    for (int i = 0; i < 8; ++i) { o0.h[i] = T[nc + i][d]; o1.h[i] = T[nc + 8 + i][d]; }
    __hip_bfloat16* dst = HT + ((size_t)b * ND + d0 + d) * NN + n0 + nc;
    *(bf16x8*)(void*)dst = o0.v;
    *(bf16x8*)(void*)(dst + 8) = o1.v;
  }
}

// =====================================================================
// K2: M = rdeg ⊙ (A·H) — identical to the 76 µs round-3 build.
// =====================================================================
__global__ __launch_bounds__(256) void k_gemmM(const __hip_bfloat16* __restrict__ Ab,
                                               const __hip_bfloat16* __restrict__ HT,
                                               const float* __restrict__ rdeg,
                                               __hip_bfloat16* __restrict__ Mb,
                                               float* __restrict__ m2p) {
  int wave = threadIdx.x >> 6, lane = threadIdx.x & 63;
  int b = blockIdx.x & 7, t = blockIdx.x >> 3;   // t in [0,32)
  int tile = t * 4 + wave;                       // [0,128)
  int rt = tile >> 3, ct = tile & 7;
  int r0 = rt * 32, c0 = ct * 32;
  int rl = lane & 15, g4 = lane >> 4;
  const __hip_bfloat16* X = Ab + (size_t)b * NN * NN;
  const __hip_bfloat16* Y = HT + (size_t)b * ND * NN;
  f32x4 acc[2][2];
#pragma unroll
  for (int i = 0; i < 2; ++i)
#pragma unroll
    for (int j = 0; j < 2; ++j) { acc[i][j][0] = 0.f; acc[i][j][1] = 0.f; acc[i][j][2] = 0.f; acc[i][j][3] = 0.f; }
#pragma unroll
  for (int kk = 0; kk < NN / 32; ++kk) {
    int kb = kk * 32 + g4 * 8;
    bf16x8 a[2], bv[2];
#pragma unroll
    for (int i = 0; i < 2; ++i)
      a[i] = *(const bf16x8*)(const void*)(X + (size_t)(r0 + i * 16 + rl) * NN + kb);
#pragma unroll
    for (int j = 0; j < 2; ++j)
      bv[j] = *(const bf16x8*)(const void*)(Y + (size_t)(c0 + j * 16 + rl) * NN + kb);
#pragma unroll
    for (int i = 0; i < 2; ++i)
#pragma unroll
      for (int j = 0; j < 2; ++j)
        acc[i][j] = __builtin_amdgcn_mfma_f32_16x16x32_bf16(a[i], bv[j], acc[i][j], 0, 0, 0);
  }
#pragma unroll
  for (int i = 0; i < 2; ++i)
#pragma unroll
    for (int r = 0; r < 4; ++r) {
      int row = r0 + i * 16 + g4 * 4 + r;
      float rd = rdeg[b * NN + row];
      float ss = 0.f;
#pragma unroll
      for (int j = 0; j < 2; ++j) {
        float m = rd * acc[i][j][r];
        int col = c0 + j * 16 + rl;
        Mb[((size_t)b * NN + row) * ND + col] = __float2bfloat16(m);
        ss += m * m;
      }
      ss = wred16(ss);
      if (rl == 0) m2p[(size_t)ct * (NB * NN) + b * NN + row] = ss;
    }
}

// =====================================================================
// K3 v7: R6's structure WITHOUT the register cap. 1024 blocks x 256 thr.
// Block = (b, 64x64 tile, hg in {0,1}).
// Phase 1: 4 waves compute G -> Gt, ONE barrier.
// Phase 2: wave w does heads hg*8+w*2+{0,1}; acc[4][4] (all indices
// compile-time); per 16-row strip: scatter to wave-private Ot slice
// (2-way bank alias = free), lgkmcnt(0), then streamer: each wave-store
// = 4 rows x 256 B contiguous = 1024 B (the fill kernel's pattern,
// 4x fewer store instrs than scalar). __launch_bounds__(256) — no
// min-waves cap, compiler free to use VGPRs for ILP (R9: cap -> VGPR 36,
// fully serialized epilogue).
// =====================================================================
__global__ __launch_bounds__(256) void k_out(const __hip_bfloat16* __restrict__ Hb,
                                             const __hip_bfloat16* __restrict__ Mb,
                                             const __hip_bfloat16* __restrict__ spb,
                                             const float* __restrict__ h2,
                                             const float* __restrict__ m2p,
                                             const float* __restrict__ sigma,
                                             float* __restrict__ out) {
  __shared__ __align__(16) float Gt[64][68];
  __shared__ __align__(16) float Ot[4][16][68];   // per-wave strip buffer
  __shared__ float h2s[64], m2s[64];
  int b = blockIdx.x & 7;
  int t2 = blockIdx.x >> 3;                 // [0,128)
  int ct = t2 & 7, rt = (t2 >> 3) & 7, hg = t2 >> 6;
  int r0 = rt * 64, c0 = ct * 64;
  int tid = threadIdx.x;
  int wave = tid >> 6, lane = tid & 63;
  int rl = lane & 15, g4 = lane >> 4;

  if (tid < 64) {
    h2s[tid] = h2[b * NN + r0 + tid];
  } else if (tid < 128) {
    int c = tid - 64;
    float s = 0.f;
#pragma unroll
    for (int p = 0; p < 8; ++p) s += m2p[(size_t)p * (NB * NN) + b * NN + c0 + c];
    m2s[c] = s;
  }
  __syncthreads();

  // ---- phase 1: G once. wave w: rows w*16..+15, all 64 cols.
  {
    const __hip_bfloat16* X = Hb + (size_t)b * NN * ND;
    const __hip_bfloat16* Y = Mb + (size_t)b * NN * ND;
    int rw = wave * 16;
    f32x4 acc[4];
#pragma unroll
    for (int j = 0; j < 4; ++j) { acc[j][0] = 0.f; acc[j][1] = 0.f; acc[j][2] = 0.f; acc[j][3] = 0.f; }
#pragma unroll
    for (int kk = 0; kk < ND / 32; ++kk) {
      int kb = kk * 32 + g4 * 8;
      bf16x8 a = *(const bf16x8*)(const void*)(X + (size_t)(r0 + rw + rl) * ND + kb);
#pragma unroll
      for (int j = 0; j < 4; ++j) {
        bf16x8 bv = *(const bf16x8*)(const void*)(Y + (size_t)(c0 + j * 16 + rl) * ND + kb);
        acc[j] = __builtin_amdgcn_mfma_f32_16x16x32_bf16(a, bv, acc[j], 0, 0, 0);
      }
    }
    float sg = sigma[0];
    float inv = 0.5f / (sg * sg);
#pragma unroll
    for (int j = 0; j < 4; ++j)
#pragma unroll
      for (int r = 0; r < 4; ++r) {
        int rowl = rw + g4 * 4 + r;
        int col = j * 16 + rl;
        float d2 = h2s[rowl] + m2s[col] - 2.0f * acc[j][r];
        Gt[rowl][col] = __expf(-d2 * inv);
      }
  }
  __syncthreads();

  // ---- phase 2: wave-private heads (hg*8 + wave*2 + {0,1})
  float (*Ow)[68] = Ot[wave];
#pragma unroll 1
  for (int hh = 0; hh < 2; ++hh) {
    int h = hg * 8 + wave * 2 + hh;
    const __hip_bfloat16* Xs = spb + ((size_t)b * NH + h) * NN * NS;
    f32x4 acc[4][4];
#pragma unroll
    for (int i = 0; i < 4; ++i)
#pragma unroll
      for (int j = 0; j < 4; ++j) { acc[i][j][0] = 0.f; acc[i][j][1] = 0.f; acc[i][j][2] = 0.f; acc[i][j][3] = 0.f; }
#pragma unroll
    for (int kk = 0; kk < NS / 32; ++kk) {
      int kb = kk * 32 + g4 * 8;
      bf16x8 a[4], bv[4];
#pragma unroll
      for (int i = 0; i < 4; ++i)
        a[i] = *(const bf16x8*)(const void*)(Xs + (size_t)(r0 + i * 16 + rl) * NS + kb);
#pragma unroll
      for (int j = 0; j < 4; ++j)
        bv[j] = *(const bf16x8*)(const void*)(Xs + (size_t)(c0 + j * 16 + rl) * NS + kb);
#pragma unroll
      for (int i = 0; i < 4; ++i)
#pragma unroll
        for (int j = 0; j < 4; ++j)
          acc[i][j] = __builtin_amdgcn_mfma_f32_16x16x32_bf16(a[i], bv[j], acc[i][j], 0, 0, 0);
    }
    float* ob = out + ((size_t)b * NH + h) * NN * NN;
    // FULLY UNROLLED strip loop: all acc indices compile-time.
#pragma unroll
    for (int i = 0; i < 4; ++i) {
#pragma unroll
      for (int j = 0; j < 4; ++j)
#pragma unroll
        for (int r = 0; r < 4; ++r)
          Ow[g4 * 4 + r][j * 16 + rl] = acc[i][j][r];
      asm volatile("s_waitcnt lgkmcnt(0)" ::: "memory");
      // streamer: 4 independent {b128 Ot read, b128 Gt read, add, dwordx4
      // store}; each wave-store = 4 rows x 256 B contiguous = 1024 B.
#pragma unroll
      for (int it = 0; it < 4; ++it) {
        int row = it * 4 + g4;
        int col = rl * 4;
        float4 o = *(const float4*)&Ow[row][col];
        float4 g = *(const float4*)&Gt[i * 16 + row][col];
        float4 w;
        w.x = g.x + o.x; w.y = g.y + o.y; w.z = g.z + o.z; w.w = g.w + o.w;
        *(float4*)&ob[(size_t)(r0 + i * 16 + row) * NN + c0 + col] = w;
      }
      asm volatile("" ::: "memory");  // keep strip i's reads before strip i+1's writes
    }
  }
}

extern "C" void kernel_launch(void* const* d_in, const int* in_sizes, int n_in,
                              void* d_out, int out_size, void* d_ws, size_t ws_size,
                              hipStream_t stream) {
  const int* pos = (const int*)d_in[0];
  const float* H = (const float*)d_in[1];
  const float* A = (const float*)d_in[2];
  const float* sigma = (const float*)d_in[3];
  const float* emb = (const float*)d_in[4];
  // d_in[5] (vt_weight) only affects the sliced-off padded row/col -> unused.
  float* out = (float*)d_out;

  char* ws = (char*)d_ws;
  size_t off = 0;
  auto alloc = [&](size_t bytes) -> void* {
    void* p = ws + off;
    off = (off + bytes + 255) & ~(size_t)255;
    return p;
  };
  __hip_bfloat16* spb = (__hip_bfloat16*)alloc((size_t)NB * NH * NN * NS * 2);
  __hip_bfloat16* Ab  = (__hip_bfloat16*)alloc((size_t)NB * NN * NN * 2);
  __hip_bfloat16* Hb  = (__hip_bfloat16*)alloc((size_t)NB * NN * ND * 2);
  __hip_bfloat16* HT  = (__hip_bfloat16*)alloc((size_t)NB * ND * NN * 2);
  __hip_bfloat16* Mb  = (__hip_bfloat16*)alloc((size_t)NB * NN * ND * 2);
  float* m2p  = (float*)alloc((size_t)8 * NB * NN * 4);
  float* rdeg = (float*)alloc((size_t)NB * NN * 4);
  float* h2   = (float*)alloc((size_t)NB * NN * 4);

  k_prep<<<3328, 256, 0, stream>>>(pos, emb, H, A, spb, Ab, Hb, HT, rdeg, h2);
  k_gemmM<<<256, 256, 0, stream>>>(Ab, HT, rdeg, Mb, m2p);
  k_out<<<1024, 256, 0, stream>>>(Hb, Mb, spb, h2, m2p, sigma, out);
}

// Round 11
// 64.138 us; speedup vs baseline: 1.5753x; 1.0973x over previous
//
#include <hip/hip_runtime.h>
#include <hip/hip_bf16.h>

#define NB 8
#define NN 512
#define NS 64
#define NH 16
#define ND 256

typedef __attribute__((ext_vector_type(8))) short bf16x8;
typedef __attribute__((ext_vector_type(4))) short bf16x4;
typedef __attribute__((ext_vector_type(4))) float f32x4;

__device__ inline float wred(float v) {
#pragma unroll
  for (int m = 32; m; m >>= 1) v += __shfl_xor(v, m, 64);
  return v;
}
__device__ inline float wred16(float v) {
#pragma unroll
  for (int m = 1; m < 16; m <<= 1) v += __shfl_xor(v, m, 64);
  return v;
}
__device__ inline ushort f2bf(float x) {
  __hip_bfloat16 h = __float2bfloat16(x);
  return *(ushort*)&h;
}

// =====================================================================
// K1: prep — identical to the 76 µs round-3 build.
// =====================================================================
__global__ __launch_bounds__(256) void k_prep(const int* __restrict__ pos,
                                              const float* __restrict__ emb,
                                              const float* __restrict__ H,
                                              const float* __restrict__ A,
                                              __hip_bfloat16* __restrict__ spb,
                                              __hip_bfloat16* __restrict__ Ab,
                                              __hip_bfloat16* __restrict__ Hb,
                                              __hip_bfloat16* __restrict__ HT,
                                              float* __restrict__ rdeg,
                                              float* __restrict__ h2) {
  __shared__ ushort T[64][68];
  int blk = blockIdx.x, tid = threadIdx.x;
  int wave = tid >> 6, lane = tid & 63;

  if (blk < 1024) {
    int t = blk * 256 + tid;               // [0, NB*NN*NS)
    int idx = pos[t];
    __hip_bfloat16* dst = spb + (size_t)t * NH;
    union { bf16x8 v; ushort h[8]; } u0, u1;
    if (idx == 0) {
#pragma unroll
      for (int i = 0; i < 8; ++i) { u0.h[i] = 0; u1.h[i] = 0; }
    } else {
      const float* er = emb + idx * NH;
#pragma unroll
      for (int i = 0; i < 8; ++i) { u0.h[i] = f2bf(er[i]); u1.h[i] = f2bf(er[8 + i]); }
    }
    *(bf16x8*)(void*)dst = u0.v;
    *(bf16x8*)(void*)(dst + 8) = u1.v;
  } else if (blk < 2048) {
    int row = (blk - 1024) * 4 + wave;     // [0, NB*NN)
    const float* ar = A + (size_t)row * NN;
    float4 v0 = *(const float4*)(ar + lane * 8);
    float4 v1 = *(const float4*)(ar + lane * 8 + 4);
    float s = v0.x + v0.y + v0.z + v0.w + v1.x + v1.y + v1.z + v1.w;
    union { bf16x8 v; ushort h[8]; } u;
    u.h[0] = f2bf(v0.x); u.h[1] = f2bf(v0.y); u.h[2] = f2bf(v0.z); u.h[3] = f2bf(v0.w);
    u.h[4] = f2bf(v1.x); u.h[5] = f2bf(v1.y); u.h[6] = f2bf(v1.z); u.h[7] = f2bf(v1.w);
    *(bf16x8*)(void*)(Ab + (size_t)row * NN + lane * 8) = u.v;
    s = wred(s);
    if (lane == 0) rdeg[row] = rsqrtf(s);
  } else if (blk < 3072) {
    int row = (blk - 2048) * 4 + wave;     // [0, NB*NN)
    const float* hr = H + (size_t)row * ND;
    float4 v = *(const float4*)(hr + lane * 4);
    float ss = v.x * v.x + v.y * v.y + v.z * v.z + v.w * v.w;
    union { bf16x4 v4; ushort h[4]; } u;
    u.h[0] = f2bf(v.x); u.h[1] = f2bf(v.y); u.h[2] = f2bf(v.z); u.h[3] = f2bf(v.w);
    *(bf16x4*)(void*)(Hb + (size_t)row * ND + lane * 4) = u.v4;
    ss = wred(ss);
    if (lane == 0) h2[row] = ss;
  } else {
    int bi = blk - 3072;                   // [0, 256)
    int b = bi >> 5, r = bi & 31;
    int d0 = (r >> 3) * 64, n0 = (r & 7) * 64;
    int n = tid >> 2, c = (tid & 3) * 16;
    const float* src = H + ((size_t)b * NN + n0 + n) * ND + d0 + c;
#pragma unroll
    for (int q = 0; q < 4; ++q) {
      float4 f = *(const float4*)(src + q * 4);
      T[n][c + q * 4 + 0] = f2bf(f.x);
      T[n][c + q * 4 + 1] = f2bf(f.y);
      T[n][c + q * 4 + 2] = f2bf(f.z);
      T[n][c + q * 4 + 3] = f2bf(f.w);
    }
    __syncthreads();
    int d = tid >> 2, nc = (tid & 3) * 16;
    union { bf16x8 v; ushort h[8]; } o0, o1;
#pragma unroll
    for (int i = 0; i < 8; ++i) { o0.h[i] = T[nc + i][d]; o1.h[i] = T[nc + 8 + i][d]; }
    __hip_bfloat16* dst = HT + ((size_t)b * ND + d0 + d) * NN + n0 + nc;
    *(bf16x8*)(void*)dst = o0.v;
    *(bf16x8*)(void*)(dst + 8) = o1.v;
  }
}

// =====================================================================
// K2: M = rdeg ⊙ (A·H) — R4's 512-block 16x32-tile variant (correctness
// proven in the passing R4 run): 2 blocks/CU for latency hiding.
// =====================================================================
__global__ __launch_bounds__(256) void k_gemmM(const __hip_bfloat16* __restrict__ Ab,
                                               const __hip_bfloat16* __restrict__ HT,
                                               const float* __restrict__ rdeg,
                                               __hip_bfloat16* __restrict__ Mb,
                                               float* __restrict__ m2p) {
  int wave = threadIdx.x >> 6, lane = threadIdx.x & 63;
  int b = blockIdx.x & 7, t = blockIdx.x >> 3;   // t in [0,64)
  int tile = t * 4 + wave;                       // [0,256) = 32 rt x 8 ct
  int rt = tile >> 3, ct = tile & 7;
  int r0 = rt * 16, c0 = ct * 32;
  int rl = lane & 15, g4 = lane >> 4;
  const __hip_bfloat16* X = Ab + (size_t)b * NN * NN;
  const __hip_bfloat16* Y = HT + (size_t)b * ND * NN;
  f32x4 acc[2];
#pragma unroll
  for (int j = 0; j < 2; ++j) { acc[j][0] = 0.f; acc[j][1] = 0.f; acc[j][2] = 0.f; acc[j][3] = 0.f; }
#pragma unroll
  for (int kk = 0; kk < NN / 32; ++kk) {
    int kb = kk * 32 + g4 * 8;
    bf16x8 a = *(const bf16x8*)(const void*)(X + (size_t)(r0 + rl) * NN + kb);
#pragma unroll
    for (int j = 0; j < 2; ++j) {
      bf16x8 bv = *(const bf16x8*)(const void*)(Y + (size_t)(c0 + j * 16 + rl) * NN + kb);
      acc[j] = __builtin_amdgcn_mfma_f32_16x16x32_bf16(a, bv, acc[j], 0, 0, 0);
    }
  }
#pragma unroll
  for (int r = 0; r < 4; ++r) {
    int row = r0 + g4 * 4 + r;
    float rd = rdeg[b * NN + row];
    float ss = 0.f;
#pragma unroll
    for (int j = 0; j < 2; ++j) {
      float m = rd * acc[j][r];
      int col = c0 + j * 16 + rl;
      Mb[((size_t)b * NN + row) * ND + col] = __float2bfloat16(m);
      ss += m * m;
    }
    ss = wred16(ss);
    if (rl == 0) m2p[(size_t)ct * (NB * NN) + b * NN + row] = ss;
  }
}

// =====================================================================
// K3 v8: 512 blocks x 512 thr (8 waves). Block = (b, rt, ct) — ALL 16
// heads, G computed ONCE per tile (R10 computed it twice via hg).
// Phase 1: waves 0-3 compute G -> Gt; waves 4-7 wait at the single
// barrier (phase 1 ~15% of block time). Phase 2: wave w does heads
// w*2+{0,1}; epilogue identical to R10's proven bounce + 1024 B
// contiguous dwordx4 stores. No launch_bounds cap (R9/R10 lesson).
// All 512 blocks co-resident -> single pass, no tail.
// =====================================================================
__global__ __launch_bounds__(512) void k_out(const __hip_bfloat16* __restrict__ Hb,
                                             const __hip_bfloat16* __restrict__ Mb,
                                             const __hip_bfloat16* __restrict__ spb,
                                             const float* __restrict__ h2,
                                             const float* __restrict__ m2p,
                                             const float* __restrict__ sigma,
                                             float* __restrict__ out) {
  __shared__ __align__(16) float Gt[64][68];
  __shared__ __align__(16) float Ot[8][16][68];   // per-wave strip buffer
  __shared__ float h2s[64], m2s[64];
  int b = blockIdx.x & 7;
  int t2 = blockIdx.x >> 3;                 // [0,64)
  int ct = t2 & 7, rt = t2 >> 3;
  int r0 = rt * 64, c0 = ct * 64;
  int tid = threadIdx.x;
  int wave = tid >> 6, lane = tid & 63;
  int rl = lane & 15, g4 = lane >> 4;

  if (tid < 64) {
    h2s[tid] = h2[b * NN + r0 + tid];
  } else if (tid < 128) {
    int c = tid - 64;
    float s = 0.f;
#pragma unroll
    for (int p = 0; p < 8; ++p) s += m2p[(size_t)p * (NB * NN) + b * NN + c0 + c];
    m2s[c] = s;
  }
  __syncthreads();

  // ---- phase 1: G once, waves 0-3 (wave w: rows w*16..+15, 64 cols).
  if (wave < 4) {
    const __hip_bfloat16* X = Hb + (size_t)b * NN * ND;
    const __hip_bfloat16* Y = Mb + (size_t)b * NN * ND;
    int rw = wave * 16;
    f32x4 acc[4];
#pragma unroll
    for (int j = 0; j < 4; ++j) { acc[j][0] = 0.f; acc[j][1] = 0.f; acc[j][2] = 0.f; acc[j][3] = 0.f; }
#pragma unroll
    for (int kk = 0; kk < ND / 32; ++kk) {
      int kb = kk * 32 + g4 * 8;
      bf16x8 a = *(const bf16x8*)(const void*)(X + (size_t)(r0 + rw + rl) * ND + kb);
#pragma unroll
      for (int j = 0; j < 4; ++j) {
        bf16x8 bv = *(const bf16x8*)(const void*)(Y + (size_t)(c0 + j * 16 + rl) * ND + kb);
        acc[j] = __builtin_amdgcn_mfma_f32_16x16x32_bf16(a, bv, acc[j], 0, 0, 0);
      }
    }
    float sg = sigma[0];
    float inv = 0.5f / (sg * sg);
#pragma unroll
    for (int j = 0; j < 4; ++j)
#pragma unroll
      for (int r = 0; r < 4; ++r) {
        int rowl = rw + g4 * 4 + r;
        int col = j * 16 + rl;
        float d2 = h2s[rowl] + m2s[col] - 2.0f * acc[j][r];
        Gt[rowl][col] = __expf(-d2 * inv);
      }
  }
  __syncthreads();

  // ---- phase 2: wave w -> heads w*2 + {0,1}
  float (*Ow)[68] = Ot[wave];
#pragma unroll 1
  for (int hh = 0; hh < 2; ++hh) {
    int h = wave * 2 + hh;
    const __hip_bfloat16* Xs = spb + ((size_t)b * NH + h) * NN * NS;
    f32x4 acc[4][4];
#pragma unroll
    for (int i = 0; i < 4; ++i)
#pragma unroll
      for (int j = 0; j < 4; ++j) { acc[i][j][0] = 0.f; acc[i][j][1] = 0.f; acc[i][j][2] = 0.f; acc[i][j][3] = 0.f; }
#pragma unroll
    for (int kk = 0; kk < NS / 32; ++kk) {
      int kb = kk * 32 + g4 * 8;
      bf16x8 a[4], bv[4];
#pragma unroll
      for (int i = 0; i < 4; ++i)
        a[i] = *(const bf16x8*)(const void*)(Xs + (size_t)(r0 + i * 16 + rl) * NS + kb);
#pragma unroll
      for (int j = 0; j < 4; ++j)
        bv[j] = *(const bf16x8*)(const void*)(Xs + (size_t)(c0 + j * 16 + rl) * NS + kb);
#pragma unroll
      for (int i = 0; i < 4; ++i)
#pragma unroll
        for (int j = 0; j < 4; ++j)
          acc[i][j] = __builtin_amdgcn_mfma_f32_16x16x32_bf16(a[i], bv[j], acc[i][j], 0, 0, 0);
    }
    float* ob = out + ((size_t)b * NH + h) * NN * NN;
    // FULLY UNROLLED strip loop: all acc indices compile-time.
#pragma unroll
    for (int i = 0; i < 4; ++i) {
#pragma unroll
      for (int j = 0; j < 4; ++j)
#pragma unroll
        for (int r = 0; r < 4; ++r)
          Ow[g4 * 4 + r][j * 16 + rl] = acc[i][j][r];
      asm volatile("s_waitcnt lgkmcnt(0)" ::: "memory");
      // streamer: each wave-store = 4 rows x 256 B contiguous = 1024 B.
#pragma unroll
      for (int it = 0; it < 4; ++it) {
        int row = it * 4 + g4;
        int col = rl * 4;
        float4 o = *(const float4*)&Ow[row][col];
        float4 g = *(const float4*)&Gt[i * 16 + row][col];
        float4 w;
        w.x = g.x + o.x; w.y = g.y + o.y; w.z = g.z + o.z; w.w = g.w + o.w;
        *(float4*)&ob[(size_t)(r0 + i * 16 + row) * NN + c0 + col] = w;
      }
      asm volatile("" ::: "memory");  // keep strip i's reads before strip i+1's writes
    }
  }
}

extern "C" void kernel_launch(void* const* d_in, const int* in_sizes, int n_in,
                              void* d_out, int out_size, void* d_ws, size_t ws_size,
                              hipStream_t stream) {
  const int* pos = (const int*)d_in[0];
  const float* H = (const float*)d_in[1];
  const float* A = (const float*)d_in[2];
  const float* sigma = (const float*)d_in[3];
  const float* emb = (const float*)d_in[4];
  // d_in[5] (vt_weight) only affects the sliced-off padded row/col -> unused.
  float* out = (float*)d_out;

  char* ws = (char*)d_ws;
  size_t off = 0;
  auto alloc = [&](size_t bytes) -> void* {
    void* p = ws + off;
    off = (off + bytes + 255) & ~(size_t)255;
    return p;
  };
  __hip_bfloat16* spb = (__hip_bfloat16*)alloc((size_t)NB * NH * NN * NS * 2);
  __hip_bfloat16* Ab  = (__hip_bfloat16*)alloc((size_t)NB * NN * NN * 2);
  __hip_bfloat16* Hb  = (__hip_bfloat16*)alloc((size_t)NB * NN * ND * 2);
  __hip_bfloat16* HT  = (__hip_bfloat16*)alloc((size_t)NB * ND * NN * 2);
  __hip_bfloat16* Mb  = (__hip_bfloat16*)alloc((size_t)NB * NN * ND * 2);
  float* m2p  = (float*)alloc((size_t)8 * NB * NN * 4);
  float* rdeg = (float*)alloc((size_t)NB * NN * 4);
  float* h2   = (float*)alloc((size_t)NB * NN * 4);

  k_prep<<<3328, 256, 0, stream>>>(pos, emb, H, A, spb, Ab, Hb, HT, rdeg, h2);
  k_gemmM<<<512, 256, 0, stream>>>(Ab, HT, rdeg, Mb, m2p);
  k_out<<<512, 512, 0, stream>>>(Hb, Mb, spb, h2, m2p, sigma, out);
}